// Round 12
// baseline (323.158 us; speedup 1.0000x reference)
//
#include <hip/hip_runtime.h>
#include <hip/hip_bf16.h>

#define NN 8192
#define EE 65536

typedef unsigned short u16;
typedef __attribute__((ext_vector_type(8))) short bf16x8;          // 8 bf16 = 4 VGPRs
typedef __attribute__((ext_vector_type(8))) unsigned short u16x8;  // 16 B load
typedef __attribute__((ext_vector_type(4))) float f32x4;

// Pre-split transposed weight table offsets (elements, shared by h/l planes)
#define OFF_W0    0        // 64 x 32
#define OFF_W1    2048     // 64 x 64
#define OFF_W2    6144     // 64 x 64
#define OFF_W3M   10240    // 512 x 96  (w3*0.125 rows 0..63 | mag*0.25 rows 64..79 | 0)
#define OFF_MAGB  59392    // 512 x 32  (wm slots 3..10, [u*8+j][k])
#define OFF_MAGC  75776    // 128 x 32  (wm slots 11..12, [u*2+j][k]) — contiguous after MAGB
#define OFF_LINS  79872    // 64 x 320
#define OFF_LINV  100352   // 64 x 512
#define OFF_SKS   133120   // 64 x 640  (skip_s reshaped [w][u*10+v], *1/fan)
#define OFF_SKV   174080   // 64 x 640  (skip_v)
#define WT_TOTAL  215040

__device__ __forceinline__ u16 f2bf(float f) {
  __hip_bfloat16 h = __float2bfloat16(f);
  return *reinterpret_cast<u16*>(&h);
}
__device__ __forceinline__ float bf2f(u16 v) {
  union { unsigned int u; float f; } x; x.u = ((unsigned int)v) << 16; return x.f;
}
__device__ __forceinline__ void split2(float x, u16& h, u16& l) {
  __hip_bfloat16 bh = __float2bfloat16(x);
  h = *reinterpret_cast<u16*>(&bh);
  float r = x - __bfloat162float(bh);
  __hip_bfloat16 bl = __float2bfloat16(r);
  l = *reinterpret_cast<u16*>(&bl);
}

#define MFMA(a, b, c) __builtin_amdgcn_mfma_f32_16x16x32_bf16((a), (b), (c), 0, 0, 0)

// ---------------------------------------------------------------------------
// FUSED edge pipeline: efm -> silu(w0) -> silu(w1) -> silu(w2) ->
//   cmbA = [h|efm]@w3m, cmbB/cmbC = efm@magB/C — ONE kernel, no h HBM traffic.
// Block = 64 edges, 256 thr = 4 waves; wave w owns rows w*16..w*16+16.
// After the single efm-staging barrier, everything is wave-private:
// MFMA C-layout (col=lane&15, row=quad*4+r) writes exactly the 16 rows the
// wave reads as A (m=lane&15), so layers chain in-place in LDS without
// barriers. B fragments are read per-lane straight from the pre-split
// transposed weight table in global (16 B/lane, L2-resident).
// Numerics identical to the unfused chain (same split-pair h quantization).
// ---------------------------------------------------------------------------
__global__ __launch_bounds__(256) void k_edge(
    const u16* __restrict__ efm_h, const u16* __restrict__ efm_l,
    const u16* __restrict__ wt_h, const u16* __restrict__ wt_l,
    u16* __restrict__ cmbA, u16* __restrict__ cmbB, u16* __restrict__ cmbC)
{
  __shared__ u16 Eh[64 * 40], El[64 * 40];   // efm, K=16 zero-padded to 32
  __shared__ u16 Hh[64 * 72], Hl[64 * 72];   // h, K=64 (stride 72 for banks/align)
  const int tid  = threadIdx.x;
  const size_t pos0 = (size_t)blockIdx.x * 64;
  const int wave = tid >> 6, lane = tid & 63;
  const int quad = lane >> 4, lrow = lane & 15;
  const int kbase = quad * 8;
  const int rw = wave * 16;

  // ---- stage efm into LDS (coalesced uint4), zero-pad k=16..31 ----
  #pragma unroll
  for (int i = 0; i < 2; ++i) {
    const int idx = tid + i * 256;           // 512 ops = 64 rows x 8 chunks
    const int r = idx >> 3, c = idx & 7;
    u16* dst = (c & 4) ? El : Eh;
    const u16* src = (c & 4) ? efm_l : efm_h;
    const int cc = c & 3;
    uint4 v = make_uint4(0u, 0u, 0u, 0u);
    if (cc < 2) v = *reinterpret_cast<const uint4*>(&src[(pos0 + r) * 16 + cc * 8]);
    *reinterpret_cast<uint4*>(&dst[r * 40 + cc * 8]) = v;
  }
  __syncthreads();

  // ---- L0: h = silu(efm @ w0), K=32 (padded), N=64 ----
  {
    const bf16x8 fah = *reinterpret_cast<const bf16x8*>(&Eh[(rw + lrow) * 40 + kbase]);
    const bf16x8 fal = *reinterpret_cast<const bf16x8*>(&El[(rw + lrow) * 40 + kbase]);
    #pragma unroll
    for (int nt = 0; nt < 4; ++nt) {
      const size_t bo = (size_t)(nt * 16 + lrow) * 32 + kbase;
      const bf16x8 fbh = *reinterpret_cast<const bf16x8*>(wt_h + OFF_W0 + bo);
      const bf16x8 fbl = *reinterpret_cast<const bf16x8*>(wt_l + OFF_W0 + bo);
      f32x4 acc = {};
      acc = MFMA(fah, fbh, acc); acc = MFMA(fah, fbl, acc); acc = MFMA(fal, fbh, acc);
      #pragma unroll
      for (int r = 0; r < 4; ++r) {
        float t = acc[r];
        t = t / (1.0f + __expf(-t));
        u16 hh, ll; split2(t, hh, ll);
        const int row = rw + quad * 4 + r, col = nt * 16 + lrow;
        Hh[row * 72 + col] = hh; Hl[row * 72 + col] = ll;
      }
    }
  }

  // ---- L1, L2: h = silu(h @ w), K=64, N=64, in-place (A loads precede writes) ----
  #pragma unroll
  for (int layer = 0; layer < 2; ++layer) {
    const int OFF = layer ? OFF_W2 : OFF_W1;
    bf16x8 fah[2], fal[2];
    #pragma unroll
    for (int ks = 0; ks < 2; ++ks) {
      fah[ks] = *reinterpret_cast<const bf16x8*>(&Hh[(rw + lrow) * 72 + ks * 32 + kbase]);
      fal[ks] = *reinterpret_cast<const bf16x8*>(&Hl[(rw + lrow) * 72 + ks * 32 + kbase]);
    }
    f32x4 acc[4] = {};
    #pragma unroll
    for (int nt = 0; nt < 4; ++nt)
      #pragma unroll
      for (int ks = 0; ks < 2; ++ks) {
        const size_t bo = (size_t)(nt * 16 + lrow) * 64 + ks * 32 + kbase;
        const bf16x8 fbh = *reinterpret_cast<const bf16x8*>(wt_h + OFF + bo);
        const bf16x8 fbl = *reinterpret_cast<const bf16x8*>(wt_l + OFF + bo);
        acc[nt] = MFMA(fah[ks], fbh, acc[nt]);
        acc[nt] = MFMA(fah[ks], fbl, acc[nt]);
        acc[nt] = MFMA(fal[ks], fbh, acc[nt]);
      }
    #pragma unroll
    for (int nt = 0; nt < 4; ++nt)
      #pragma unroll
      for (int r = 0; r < 4; ++r) {
        float t = acc[nt][r];
        t = t / (1.0f + __expf(-t));
        u16 hh, ll; split2(t, hh, ll);
        const int row = rw + quad * 4 + r, col = nt * 16 + lrow;
        Hh[row * 72 + col] = hh; Hl[row * 72 + col] = ll;
      }
  }

  // ---- cmbA = [h | efm] @ w3m, K=96, N=512 (8 col-groups) ----
  {
    bf16x8 fah[3], fal[3];
    #pragma unroll
    for (int ks = 0; ks < 2; ++ks) {
      fah[ks] = *reinterpret_cast<const bf16x8*>(&Hh[(rw + lrow) * 72 + ks * 32 + kbase]);
      fal[ks] = *reinterpret_cast<const bf16x8*>(&Hl[(rw + lrow) * 72 + ks * 32 + kbase]);
    }
    fah[2] = *reinterpret_cast<const bf16x8*>(&Eh[(rw + lrow) * 40 + kbase]);
    fal[2] = *reinterpret_cast<const bf16x8*>(&El[(rw + lrow) * 40 + kbase]);
    for (int g = 0; g < 8; ++g) {
      #pragma unroll
      for (int nt = 0; nt < 4; ++nt) {
        f32x4 acc = {};
        #pragma unroll
        for (int ks = 0; ks < 3; ++ks) {
          const size_t bo = (size_t)(g * 64 + nt * 16 + lrow) * 96 + ks * 32 + kbase;
          const bf16x8 fbh = *reinterpret_cast<const bf16x8*>(wt_h + OFF_W3M + bo);
          const bf16x8 fbl = *reinterpret_cast<const bf16x8*>(wt_l + OFF_W3M + bo);
          acc = MFMA(fah[ks], fbh, acc); acc = MFMA(fah[ks], fbl, acc); acc = MFMA(fal[ks], fbh, acc);
        }
        const int col = g * 64 + nt * 16 + lrow;
        #pragma unroll
        for (int r = 0; r < 4; ++r) {
          const size_t row = pos0 + rw + quad * 4 + r;
          cmbA[row * 512 + col] = f2bf(acc[r]);
        }
      }
    }
  }

  // ---- cmbB/cmbC = efm @ [magB ; magC], K=32 (padded), N=640 (10 groups) ----
  {
    const bf16x8 fah = *reinterpret_cast<const bf16x8*>(&Eh[(rw + lrow) * 40 + kbase]);
    const bf16x8 fal = *reinterpret_cast<const bf16x8*>(&El[(rw + lrow) * 40 + kbase]);
    for (int g = 0; g < 10; ++g) {
      #pragma unroll
      for (int nt = 0; nt < 4; ++nt) {
        const int col = g * 64 + nt * 16 + lrow;
        const size_t bo = (size_t)col * 32 + kbase;
        const bf16x8 fbh = *reinterpret_cast<const bf16x8*>(wt_h + OFF_MAGB + bo);
        const bf16x8 fbl = *reinterpret_cast<const bf16x8*>(wt_l + OFF_MAGB + bo);
        f32x4 acc = {};
        acc = MFMA(fah, fbh, acc); acc = MFMA(fah, fbl, acc); acc = MFMA(fal, fbh, acc);
        #pragma unroll
        for (int r = 0; r < 4; ++r) {
          const size_t row = pos0 + rw + quad * 4 + r;
          if (col < 512) cmbB[row * 512 + col] = f2bf(acc[r]);
          else           cmbC[row * 128 + col - 512] = f2bf(acc[r]);
        }
      }
    }
  }
}

// ---------------------------------------------------------------------------
// MFMA GEMM, fp32-equivalent via 3-term bf16 split (kept for the node linears).
// RT=32: 4 waves side-by-side over cols (2x1 tiles/wave).
// OUT: 0 = fp32. DDIV: post *= 1/(dens[row/DDIV]+1).
// ---------------------------------------------------------------------------
template<int RT, int OUT, bool SILU, int DDIV>
__global__ __launch_bounds__(256) void k_mgemm(
    const u16* __restrict__ X1h, const u16* __restrict__ X1l, int x1rs, int K1,
    const u16* __restrict__ X2h, const u16* __restrict__ X2l, int x2rs, int K2,
    const u16* __restrict__ Wth, const u16* __restrict__ Wtl, int K,
    void* __restrict__ O1, void* __restrict__ O2, int ors,
    const float* __restrict__ dens)
{
  constexpr int NTN = (RT == 128) ? 4 : 1;
  constexpr int AIT = RT * 8 / 256;
  __shared__ u16 Ah[RT * 40];
  __shared__ u16 Al[RT * 40];
  __shared__ u16 Bh[64 * 40];
  __shared__ u16 Bl[64 * 40];
  const int tid  = threadIdx.x;
  const int row0 = blockIdx.x * RT;
  const int col0 = blockIdx.y * 64;
  const int wave = tid >> 6, lane = tid & 63;
  const int quad = lane >> 4, lrow = lane & 15;
  const int kbase = quad * 8;
  const int rw  = (RT == 128) ? wave * 32 : 0;
  const int ntb = (RT == 128) ? 0 : wave;

  f32x4 acc[2][NTN] = {};

  for (int k0 = 0; k0 < K; k0 += 32) {
    #pragma unroll
    for (int i = 0; i < AIT; ++i) {
      const int idx = tid + i * 256;
      const int b = idx / (RT * 4), rc = idx & (RT * 4 - 1);
      const int r = rc >> 2, c = rc & 3;
      const int gk = k0 + c * 8;
      uint4 v = make_uint4(0u, 0u, 0u, 0u);
      if (gk < K1)
        v = *reinterpret_cast<const uint4*>(&(b ? X1l : X1h)[(size_t)(row0 + r) * x1rs + gk]);
      else if (gk - K1 < K2)
        v = *reinterpret_cast<const uint4*>(&(b ? X2l : X2h)[(size_t)(row0 + r) * x2rs + gk - K1]);
      *reinterpret_cast<uint4*>(&(b ? Al : Ah)[r * 40 + c * 8]) = v;
    }
    #pragma unroll
    for (int i = 0; i < 2; ++i) {
      const int idx = tid + i * 256;
      const int b = idx >> 8, rc = idx & 255;
      const int n = rc >> 2, c = rc & 3;
      const uint4 v = *reinterpret_cast<const uint4*>(
          &(b ? Wtl : Wth)[(size_t)(col0 + n) * K + k0 + c * 8]);
      *reinterpret_cast<uint4*>(&(b ? Bl : Bh)[n * 40 + c * 8]) = v;
    }
    __syncthreads();

    bf16x8 fah[2], fal[2], fbh[NTN], fbl[NTN];
    #pragma unroll
    for (int mt = 0; mt < 2; ++mt) {
      const int ro = (rw + mt * 16 + lrow) * 40 + kbase;
      fah[mt] = *reinterpret_cast<const bf16x8*>(&Ah[ro]);
      fal[mt] = *reinterpret_cast<const bf16x8*>(&Al[ro]);
    }
    #pragma unroll
    for (int nt = 0; nt < NTN; ++nt) {
      const int ro = ((ntb + nt) * 16 + lrow) * 40 + kbase;
      fbh[nt] = *reinterpret_cast<const bf16x8*>(&Bh[ro]);
      fbl[nt] = *reinterpret_cast<const bf16x8*>(&Bl[ro]);
    }
    #pragma unroll
    for (int mt = 0; mt < 2; ++mt)
      #pragma unroll
      for (int nt = 0; nt < NTN; ++nt) {
        acc[mt][nt] = MFMA(fah[mt], fbh[nt], acc[mt][nt]);
        acc[mt][nt] = MFMA(fah[mt], fbl[nt], acc[mt][nt]);
        acc[mt][nt] = MFMA(fal[mt], fbh[nt], acc[mt][nt]);
      }
    __syncthreads();
  }

  #pragma unroll
  for (int mt = 0; mt < 2; ++mt)
    #pragma unroll
    for (int nt = 0; nt < NTN; ++nt)
      #pragma unroll
      for (int r = 0; r < 4; ++r) {
        const int grow = row0 + rw + mt * 16 + quad * 4 + r;
        const int gcol = col0 + (ntb + nt) * 16 + lrow;
        float t = acc[mt][nt][r];
        if (SILU) t = t / (1.0f + __expf(-t));
        if (DDIV > 0) t *= 1.0f / (dens[grow / DDIV] + 1.0f);
        const size_t oi = (size_t)grow * ors + gcol;
        if (OUT == 0) {
          reinterpret_cast<float*>(O1)[oi] = t;
        } else if (OUT == 1) {
          u16 hh, ll;
          split2(t, hh, ll);
          reinterpret_cast<u16*>(O1)[oi] = hh;
          reinterpret_cast<u16*>(O2)[oi] = ll;
        } else {
          reinterpret_cast<u16*>(O1)[oi] = f2bf(t);
        }
      }
}

// ---------------------------------------------------------------------------
// Skip contraction as MFMA GEMM, MERGED, writing DIRECTLY into out (N,64,4).
// ---------------------------------------------------------------------------
__global__ __launch_bounds__(256) void k_skipm(
    const float* __restrict__ ms2, const float* __restrict__ mv2,
    const float* __restrict__ na,
    const u16* __restrict__ wt_h, const u16* __restrict__ wt_l,
    float* __restrict__ out)
{
  __shared__ u16 Ah[32 * 40];
  __shared__ u16 Al[32 * 40];
  __shared__ u16 Bh[64 * 40];
  __shared__ u16 Bl[64 * 40];
  const int tid  = threadIdx.x;
  const bool isv = blockIdx.x >= (NN / 32);
  const int row0 = (isv ? (blockIdx.x - NN / 32) : blockIdx.x) * 32;
  const float* C = isv ? mv2 : ms2;
  const u16* Bth = wt_h + (isv ? OFF_SKV : OFF_SKS);
  const u16* Btl = wt_l + (isv ? OFF_SKV : OFF_SKS);
  const int wave = tid >> 6, lane = tid & 63;
  const int quad = lane >> 4, lrow = lane & 15;
  const int kbase = quad * 8;

  f32x4 acc[2] = {};

  for (int k0 = 0; k0 < 640; k0 += 32) {
    #pragma unroll
    for (int i = 0; i < 4; ++i) {
      const int e = tid + i * 256;
      const int r = e >> 5, kk = e & 31;
      const int k = k0 + kk;
      const int u = k / 10, v = k - u * 10;
      const int row = row0 + r;
      const int n = isv ? (row / 3) : row;
      const float t = C[(size_t)row * 64 + u] * na[n * 10 + v];
      u16 hh, ll;
      split2(t, hh, ll);
      Ah[r * 40 + kk] = hh;
      Al[r * 40 + kk] = ll;
    }
    #pragma unroll
    for (int i = 0; i < 2; ++i) {
      const int idx = tid + i * 256;
      const int b = idx >> 8, rc = idx & 255;
      const int nw = rc >> 2, c = rc & 3;
      const uint4 v4 = *reinterpret_cast<const uint4*>(
          &(b ? Btl : Bth)[(size_t)nw * 640 + k0 + c * 8]);
      *reinterpret_cast<uint4*>(&(b ? Bl : Bh)[nw * 40 + c * 8]) = v4;
    }
    __syncthreads();

    bf16x8 fah[2], fal[2], fbh, fbl;
    #pragma unroll
    for (int mt = 0; mt < 2; ++mt) {
      const int ro = (mt * 16 + lrow) * 40 + kbase;
      fah[mt] = *reinterpret_cast<const bf16x8*>(&Ah[ro]);
      fal[mt] = *reinterpret_cast<const bf16x8*>(&Al[ro]);
    }
    {
      const int ro = (wave * 16 + lrow) * 40 + kbase;
      fbh = *reinterpret_cast<const bf16x8*>(&Bh[ro]);
      fbl = *reinterpret_cast<const bf16x8*>(&Bl[ro]);
    }
    #pragma unroll
    for (int mt = 0; mt < 2; ++mt) {
      acc[mt] = MFMA(fah[mt], fbh, acc[mt]);
      acc[mt] = MFMA(fah[mt], fbl, acc[mt]);
      acc[mt] = MFMA(fal[mt], fbh, acc[mt]);
    }
    __syncthreads();
  }

  #pragma unroll
  for (int mt = 0; mt < 2; ++mt)
    #pragma unroll
    for (int r = 0; r < 4; ++r) {
      const int row = row0 + mt * 16 + quad * 4 + r;
      const int w = wave * 16 + lrow;
      if (isv) {
        const int n = row / 3, i = row - n * 3;
        out[(size_t)n * 256 + w * 4 + 1 + i] = acc[mt][r];
      } else {
        out[(size_t)row * 256 + w * 4] = acc[mt][r];
      }
    }
}

// ---------------------------------------------------------------------------
// fp32 tiled GEMM (node up-projections): OUT = scale * X@W
// ---------------------------------------------------------------------------
template<int RT>
__global__ __launch_bounds__(256) void k_gemm(
    const float* __restrict__ X, int xrs, int xes, int xco, int xcob,
    const float* __restrict__ W, int K, int NOUT,
    float scale, float* __restrict__ OUTp, int ors, int oob)
{
  constexpr int RPT = RT / 16;
  __shared__ float Xs[RT * 65];
  __shared__ float Ws[64 * 64];
  const int tid  = threadIdx.x;
  const int row0 = blockIdx.x * RT;
  const int col0 = blockIdx.y * 64;
  const int z    = blockIdx.z;
  const int xc   = xco + z * xcob;
  const int oo   = z * oob;
  const int ci = tid & 15;
  const int ri = tid >> 4;
  float acc[RPT][4] = {};

  for (int k0 = 0; k0 < K; k0 += 64) {
    const int kc  = (K - k0 >= 64) ? 64 : (K - k0);
    const int ksh = (kc == 64) ? 6 : 4;
    for (int idx = tid; idx < kc * RT; idx += 256) {
      const int r = idx >> ksh, kk = idx & (kc - 1);
      Xs[r * 65 + kk] = X[(size_t)(row0 + r) * xrs + xc + (size_t)(k0 + kk) * xes];
    }
    for (int idx = tid; idx < (kc << 6); idx += 256) {
      const int kk = idx >> 6, c = idx & 63;
      Ws[kk * 64 + c] = W[(size_t)(k0 + kk) * NOUT + col0 + c];
    }
    __syncthreads();
    for (int kk = 0; kk < kc; ++kk) {
      const float4 wv = *reinterpret_cast<const float4*>(&Ws[kk * 64 + ci * 4]);
      #pragma unroll
      for (int j = 0; j < RPT; ++j) {
        const float x = Xs[(ri * RPT + j) * 65 + kk];
        acc[j][0] += x * wv.x; acc[j][1] += x * wv.y;
        acc[j][2] += x * wv.z; acc[j][3] += x * wv.w;
      }
    }
    __syncthreads();
  }

  #pragma unroll
  for (int j = 0; j < RPT; ++j) {
    const int row = row0 + ri * RPT + j;
    *reinterpret_cast<float4*>(OUTp + (size_t)row * ors + oo + col0 + ci * 4) =
        make_float4(acc[j][0] * scale, acc[j][1] * scale, acc[j][2] * scale, acc[j][3] * scale);
  }
}

// ---------------------------------------------------------------------------
// CSR build
// ---------------------------------------------------------------------------
__global__ __launch_bounds__(256) void k_count(const int* __restrict__ rcv, int* __restrict__ counts) {
  const int e = blockIdx.x * 256 + threadIdx.x;
  atomicAdd(&counts[rcv[e]], 1);
}

__global__ __launch_bounds__(1024) void k_scan(const int* __restrict__ counts,
                                               int* __restrict__ offs, int* __restrict__ cursor) {
  __shared__ int part[1024];
  const int tid = threadIdx.x;
  int local[8];
  int s = 0;
  #pragma unroll
  for (int j = 0; j < 8; ++j) { local[j] = s; s += counts[tid * 8 + j]; }
  part[tid] = s;
  __syncthreads();
  for (int off = 1; off < 1024; off <<= 1) {
    int v = 0;
    if (tid >= off) v = part[tid - off];
    __syncthreads();
    part[tid] += v;
    __syncthreads();
  }
  const int base = part[tid] - s;
  #pragma unroll
  for (int j = 0; j < 8; ++j) {
    const int o = base + local[j];
    offs[tid * 8 + j] = o;
    cursor[tid * 8 + j] = o;
  }
  if (tid == 1023) offs[NN] = part[1023];
}

__global__ __launch_bounds__(256) void k_fill(const int* __restrict__ rcv,
                                              int* __restrict__ cursor, int* __restrict__ perm) {
  const int e = blockIdx.x * 256 + threadIdx.x;
  const int pos = atomicAdd(&cursor[rcv[e]], 1);
  perm[pos] = e;
}

// ---------------------------------------------------------------------------
// Build the pre-split, pre-scaled, TRANSPOSED weight table (one pass, ~0.9 MB).
// ---------------------------------------------------------------------------
__global__ __launch_bounds__(256) void k_permw(
    const float* __restrict__ w0, const float* __restrict__ w1,
    const float* __restrict__ w2, const float* __restrict__ w3,
    const float* __restrict__ mag_w, const float* __restrict__ lin_s,
    const float* __restrict__ lin_v, const float* __restrict__ skip_s,
    const float* __restrict__ skip_v,
    u16* __restrict__ wt_h, u16* __restrict__ wt_l)
{
  const int id = blockIdx.x * 256 + threadIdx.x;   // WT_TOTAL threads
  float val = 0.f;
  if (id < OFF_W1) {
    const int i = id - OFF_W0, n = i >> 5, k = i & 31;
    val = (k < 16) ? w0[k * 64 + n] * 0.25f : 0.f;
  } else if (id < OFF_W2) {
    const int i = id - OFF_W1, n = i >> 6, k = i & 63;
    val = w1[k * 64 + n] * 0.125f;
  } else if (id < OFF_W3M) {
    const int i = id - OFF_W2, n = i >> 6, k = i & 63;
    val = w2[k * 64 + n] * 0.125f;
  } else if (id < OFF_MAGB) {
    const int i = id - OFF_W3M, n = i / 96, k = i - n * 96;
    const int u = n >> 3, j = n & 7;
    if (k < 64)      val = (j < 5)  ? w3[k * 320 + j * 64 + u] * 0.125f : 0.f;
    else if (k < 80) val = (j >= 5) ? mag_w[(k - 64) * 832 + (j - 5) * 64 + u] * 0.25f : 0.f;
  } else if (id < OFF_MAGC) {
    const int i = id - OFF_MAGB, n = i >> 5, k = i & 31;
    const int u = n >> 3, j = n & 7;
    val = (k < 16) ? mag_w[k * 832 + (j + 3) * 64 + u] * 0.25f : 0.f;
  } else if (id < OFF_LINS) {
    const int i = id - OFF_MAGC, n = i >> 5, k = i & 31;
    const int u = n >> 1, j = n & 1;
    val = (k < 16) ? mag_w[k * 832 + (j + 11) * 64 + u] * 0.25f : 0.f;
  } else if (id < OFF_LINV) {
    const int i = id - OFF_LINS, n = i / 320, k = i - n * 320;
    val = lin_s[k * 64 + n] * 0.05590169944f;
  } else if (id < OFF_SKS) {
    const int i = id - OFF_LINV, n = i >> 9, k = i & 511;
    val = lin_v[k * 64 + n] * 0.04419417382f;
  } else if (id < OFF_SKV) {
    const int i = id - OFF_SKS, w = i / 640, k = i - w * 640;
    val = skip_s[k * 64 + w] * 0.03952847075f;   // [u*10+v][w], 1/sqrt(640)
  } else if (id < WT_TOTAL) {
    const int i = id - OFF_SKV, w = i / 640, k = i - w * 640;
    val = skip_v[k * 64 + w] * 0.03952847075f;
  } else {
    return;
  }
  u16 hh, ll;
  split2(val, hh, ll);
  wt_h[id] = hh;
  wt_l[id] = ll;
}

// ---------------------------------------------------------------------------
// Permute edge data into receiver-grouped (perm) order + precompute:
//   snd_perm, ya_perm, dq_perm (tanh(q^2)), efm split pair.
// ---------------------------------------------------------------------------
__global__ __launch_bounds__(256) void k_build(
    const int* __restrict__ perm, const int* __restrict__ snd,
    const float* __restrict__ edge_attrs, const float* __restrict__ edge_feats,
    const float* __restrict__ mm_inv, const float* __restrict__ dens_w,
    int* __restrict__ snd_perm, float* __restrict__ ya_perm,
    float* __restrict__ dq_perm, u16* __restrict__ efm_h, u16* __restrict__ efm_l)
{
  const int pos = blockIdx.x * 256 + threadIdx.x;
  const int e = perm[pos];
  const int s = snd[e];
  snd_perm[pos] = s;
  reinterpret_cast<float4*>(ya_perm)[pos] = reinterpret_cast<const float4*>(edge_attrs)[e];
  const float4 ef0 = reinterpret_cast<const float4*>(edge_feats)[e * 2];
  const float4 ef1 = reinterpret_cast<const float4*>(edge_feats)[e * 2 + 1];
  const float4 mi0 = reinterpret_cast<const float4*>(mm_inv)[s * 2];
  const float4 mi1 = reinterpret_cast<const float4*>(mm_inv)[s * 2 + 1];
  float q = ef0.x * dens_w[0] + ef0.y * dens_w[1] + ef0.z * dens_w[2] + ef0.w * dens_w[3]
          + ef1.x * dens_w[4] + ef1.y * dens_w[5] + ef1.z * dens_w[6] + ef1.w * dens_w[7];
  q *= 0.35355339059f;   // 1/sqrt(8)
  dq_perm[pos] = tanhf(q * q);
  float vals[16] = { ef0.x, ef0.y, ef0.z, ef0.w, ef1.x, ef1.y, ef1.z, ef1.w,
                     mi0.x, mi0.y, mi0.z, mi0.w, mi1.x, mi1.y, mi1.z, mi1.w };
  u16 hh[16], ll[16];
  #pragma unroll
  for (int i = 0; i < 16; ++i) split2(vals[i], hh[i], ll[i]);
  reinterpret_cast<uint4*>(&efm_h[(size_t)pos * 16])[0] = reinterpret_cast<uint4*>(hh)[0];
  reinterpret_cast<uint4*>(&efm_h[(size_t)pos * 16])[1] = reinterpret_cast<uint4*>(hh)[1];
  reinterpret_cast<uint4*>(&efm_l[(size_t)pos * 16])[0] = reinterpret_cast<uint4*>(ll)[0];
  reinterpret_cast<uint4*>(&efm_l[(size_t)pos * 16])[1] = reinterpret_cast<uint4*>(ll)[1];
}

// ---------------------------------------------------------------------------
// Gather: TWO half-waves per node (halved serial edge chain, LDS reduction).
// ---------------------------------------------------------------------------
__global__ __launch_bounds__(256) void k_gather(
    const int* __restrict__ snd_perm,
    const float* __restrict__ ya_perm,
    const float* __restrict__ dq_perm,
    const float* __restrict__ mm_attrs,
    const float* __restrict__ s_buf,
    const float* __restrict__ v_buf,
    const u16* __restrict__ cmbA,
    const u16* __restrict__ cmbB,
    const u16* __restrict__ cmbC,
    const int* __restrict__ offs,
    u16* __restrict__ ms_h, u16* __restrict__ ms_l,
    u16* __restrict__ mv_h, u16* __restrict__ mv_l,
    float* __restrict__ dens)
{
  __shared__ float red[2][30][64];
  const int tid  = threadIdx.x;
  const int lane = tid & 63;
  const int nib  = tid >> 7;                 // node within block (0/1)
  const int half = (tid >> 6) & 1;           // segment half (0/1)
  const int n = blockIdx.x * 2 + nib;

  float acc_s[5] = {0.f, 0.f, 0.f, 0.f, 0.f};
  float acc_v[8][3] = {};
  float dacc = 0.f;
  const int start0 = offs[n], end0 = offs[n + 1];
  const int mid = start0 + ((end0 - start0 + 1) >> 1);
  const int start = half ? mid : start0;
  const int end   = half ? end0 : mid;

  int s_nx = 0;
  if (start < end) s_nx = snd_perm[start];
  for (int pos = start; pos < end; ++pos) {
    const int s = s_nx;
    if (pos + 1 < end) s_nx = snd_perm[pos + 1];

    const float4 ya = reinterpret_cast<const float4*>(ya_perm)[pos];
    const float4 mm = reinterpret_cast<const float4*>(mm_attrs)[s];
    dacc += dq_perm[pos];
    const float y0 = ya.x, y1x = ya.y, y1y = ya.z, y1z = ya.w;
    const float m0 = mm.x, m1x = mm.y, m1y = mm.z, m1z = mm.w;
    const float xs  = s_buf[s * 64 + lane];
    const float xvx = v_buf[(s * 3 + 0) * 64 + lane];
    const float xvy = v_buf[(s * 3 + 1) * 64 + lane];
    const float xvz = v_buf[(s * 3 + 2) * 64 + lane];

    const u16x8 ca = *reinterpret_cast<const u16x8*>(&cmbA[((size_t)pos * 64 + lane) * 8]);
    const u16x8 cb = *reinterpret_cast<const u16x8*>(&cmbB[((size_t)pos * 64 + lane) * 8]);
    const unsigned int cc = *reinterpret_cast<const unsigned int*>(&cmbC[((size_t)pos * 64 + lane) * 2]);
    float tpv[5];
    #pragma unroll
    for (int j = 0; j < 5; ++j) tpv[j] = bf2f(ca[j]);
    float wv[13];
    #pragma unroll
    for (int p = 0; p < 3; ++p) wv[p] = bf2f(ca[5 + p]);
    #pragma unroll
    for (int p = 3; p < 11; ++p) wv[p] = bf2f(cb[p - 3]);
    wv[11] = bf2f((u16)(cc & 0xffffu));
    wv[12] = bf2f((u16)(cc >> 16));

    const float ms0  = tpv[0] * xs * y0;
    const float mv0x = tpv[1] * xs * y1x, mv0y = tpv[1] * xs * y1y, mv0z = tpv[1] * xs * y1z;
    const float mv1x = tpv[2] * xvx * y0, mv1y = tpv[2] * xvy * y0, mv1z = tpv[2] * xvz * y0;
    const float ms1  = tpv[3] * (xvx * y1x + xvy * y1y + xvz * y1z) * 0.57735026919f;
    const float crx = xvy * y1z - xvz * y1y;
    const float cry = xvz * y1x - xvx * y1z;
    const float crz = xvx * y1y - xvy * y1x;
    const float mv2x = tpv[4] * crx * 0.70710678119f;
    const float mv2y = tpv[4] * cry * 0.70710678119f;
    const float mv2z = tpv[4] * crz * 0.70710678119f;

    acc_s[0]    += wv[0] * ms0 * m0;
    acc_v[0][0] += wv[1] * ms0 * m1x; acc_v[0][1] += wv[1] * ms0 * m1y; acc_v[0][2] += wv[1] * ms0 * m1z;
    acc_s[1]    += wv[2] * ms1 * m0;
    acc_v[1][0] += wv[3] * ms1 * m1x; acc_v[1][1] += wv[3] * ms1 * m1y; acc_v[1][2] += wv[3] * ms1 * m1z;

#define VV_BLOCK(vx, vy, vz, pw, vslotA, sslot, vslotB)                                   \
    acc_v[vslotA][0] += wv[pw] * (vx) * m0;                                               \
    acc_v[vslotA][1] += wv[pw] * (vy) * m0;                                               \
    acc_v[vslotA][2] += wv[pw] * (vz) * m0;                                               \
    acc_s[sslot] += wv[pw + 1] * ((vx) * m1x + (vy) * m1y + (vz) * m1z) * 0.57735026919f; \
    {                                                                                     \
      const float ccx = (vy) * m1z - (vz) * m1y;                                          \
      const float ccy = (vz) * m1x - (vx) * m1z;                                          \
      const float ccz = (vx) * m1y - (vy) * m1x;                                          \
      acc_v[vslotB][0] += wv[pw + 2] * ccx * 0.70710678119f;                              \
      acc_v[vslotB][1] += wv[pw + 2] * ccy * 0.70710678119f;                              \
      acc_v[vslotB][2] += wv[pw + 2] * ccz * 0.70710678119f;                              \
    }

    VV_BLOCK(mv0x, mv0y, mv0z, 4, 2, 2, 3)
    VV_BLOCK(mv1x, mv1y, mv1z, 7, 4, 3, 5)
    VV_BLOCK(mv2x, mv2y, mv2z, 10, 6, 4, 7)
#undef VV_BLOCK
  }

  // ---- combine the two half-waves of each node via LDS ----
  if (half == 1) {
    #pragma unroll
    for (int j = 0; j < 5; ++j) red[nib][j][lane] = acc_s[j];
    #pragma unroll
    for (int p = 0; p < 8; ++p)
      #pragma unroll
      for (int i = 0; i < 3; ++i) red[nib][5 + p * 3 + i][lane] = acc_v[p][i];
    red[nib][29][lane] = dacc;
  }
  __syncthreads();
  if (half == 0) {
    #pragma unroll
    for (int j = 0; j < 5; ++j) acc_s[j] += red[nib][j][lane];
    #pragma unroll
    for (int p = 0; p < 8; ++p)
      #pragma unroll
      for (int i = 0; i < 3; ++i) acc_v[p][i] += red[nib][5 + p * 3 + i][lane];
    dacc += red[nib][29][lane];

    #pragma unroll
    for (int j = 0; j < 5; ++j) {
      u16 hh, ll;
      split2(acc_s[j], hh, ll);
      ms_h[(size_t)n * 320 + j * 64 + lane] = hh;
      ms_l[(size_t)n * 320 + j * 64 + lane] = ll;
    }
    #pragma unroll
    for (int p = 0; p < 8; ++p)
      #pragma unroll
      for (int i = 0; i < 3; ++i) {
        u16 hh, ll;
        split2(acc_v[p][i], hh, ll);
        mv_h[((size_t)n * 3 + i) * 512 + p * 64 + lane] = hh;
        mv_l[((size_t)n * 3 + i) * 512 + p * 64 + lane] = ll;
      }
    if (lane == 0) dens[n] = dacc;
  }
}

// ---------------------------------------------------------------------------
extern "C" void kernel_launch(void* const* d_in, const int* in_sizes, int n_in,
                              void* d_out, int out_size, void* d_ws, size_t ws_size,
                              hipStream_t stream)
{
  const float* node_attrs = (const float*)d_in[0];
  const float* node_feats = (const float*)d_in[1];
  const float* edge_attrs = (const float*)d_in[2];
  const float* edge_feats = (const float*)d_in[3];
  const int*   edge_index = (const int*)d_in[4];
  const float* mm_inv     = (const float*)d_in[5];
  const float* mm_attrs   = (const float*)d_in[6];
  const float* W_up_s     = (const float*)d_in[7];
  const float* W_up_v     = (const float*)d_in[8];
  const float* w0         = (const float*)d_in[9];
  const float* w1         = (const float*)d_in[10];
  const float* w2         = (const float*)d_in[11];
  const float* w3         = (const float*)d_in[12];
  const float* mag_w      = (const float*)d_in[13];
  const float* dens_w     = (const float*)d_in[14];
  const float* lin_s      = (const float*)d_in[15];
  const float* lin_v      = (const float*)d_in[16];
  const float* skip_s     = (const float*)d_in[17];
  const float* skip_v     = (const float*)d_in[18];
  float* out = (float*)d_out;

  char* wp = (char*)d_ws;
  auto alloc = [&](size_t b) { char* p = wp; wp += (b + 255) & ~(size_t)255; return p; };
  // Total footprint ~250 MB (R11-identical layout).
  float* s_buf  = (float*)alloc((size_t)NN * 64 * 4);       // 2.10 MB
  float* v_buf  = (float*)alloc((size_t)NN * 192 * 4);      // 6.29 MB
  float* ya_p   = (float*)alloc((size_t)EE * 4 * 4);        // 1.05 MB
  float* dq_p   = (float*)alloc((size_t)EE * 4);            // 0.26 MB
  int*   snd_p  = (int*)alloc((size_t)EE * 4);              // 0.26 MB
  u16*   efm_h  = (u16*)alloc((size_t)EE * 16 * 2);         // 2.10 MB
  u16*   efm_l  = (u16*)alloc((size_t)EE * 16 * 2);         // 2.10 MB
  u16*   hA_h   = (u16*)alloc((size_t)EE * 64 * 2);         // 8.39 MB (ms2/mv2 backing)
  u16*   hA_l   = (u16*)alloc((size_t)EE * 64 * 2);         // 8.39 MB
  u16*   hB_h   = (u16*)alloc((size_t)EE * 64 * 2);         // 8.39 MB (ms backing)
  u16*   hB_l   = (u16*)alloc((size_t)EE * 64 * 2);         // 8.39 MB
  u16*   cmbA   = (u16*)alloc((size_t)EE * 512 * 2);        // 67.1 MB
  u16*   cmbB   = (u16*)alloc((size_t)EE * 512 * 2);        // 67.1 MB
  u16*   cmbC   = (u16*)alloc((size_t)EE * 128 * 2);        // 16.8 MB
  u16*   mv_h   = (u16*)alloc((size_t)NN * 1536 * 2);       // 25.2 MB
  u16*   mv_l   = (u16*)alloc((size_t)NN * 1536 * 2);       // 25.2 MB
  float* dens   = (float*)alloc((size_t)NN * 4);
  int*   counts = (int*)alloc((size_t)NN * 4);
  int*   offs   = (int*)alloc((size_t)(NN + 1) * 4);
  int*   cursor = (int*)alloc((size_t)NN * 4);
  int*   perm   = (int*)alloc((size_t)EE * 4);
  u16*   wt_h   = (u16*)alloc((size_t)WT_TOTAL * 2);        // 0.43 MB
  u16*   wt_l   = (u16*)alloc((size_t)WT_TOTAL * 2);        // 0.43 MB
  u16*   ms_h   = hB_h;            // NN*320*2 = 5.25 MB <= 8.39 MB
  u16*   ms_l   = hB_l;
  float* ms2    = (float*)hA_h;    // 2.10 MB <= 8.39 MB
  float* mv2    = (float*)hA_l;    // 6.29 MB <= 8.39 MB

  const int* snd = edge_index;
  const int* rcv = edge_index + EE;

  // CSR + permuted edge data + pre-split transposed weight table
  hipMemsetAsync(counts, 0, (size_t)NN * 4, stream);
  k_count<<<EE / 256, 256, 0, stream>>>(rcv, counts);
  k_scan<<<1, 1024, 0, stream>>>(counts, offs, cursor);
  k_fill<<<EE / 256, 256, 0, stream>>>(rcv, cursor, perm);
  k_build<<<EE / 256, 256, 0, stream>>>(perm, snd, edge_attrs, edge_feats, mm_inv, dens_w,
                                        snd_p, ya_p, dq_p, efm_h, efm_l);
  k_permw<<<(WT_TOTAL + 255) / 256, 256, 0, stream>>>(w0, w1, w2, w3, mag_w, lin_s, lin_v,
                                                     skip_s, skip_v, wt_h, wt_l);

  // node up-projections (fp32 path)
  k_gemm<32><<<dim3(NN / 32, 1, 1), 256, 0, stream>>>(
      node_feats, 256, 1, 0, 0, W_up_s, 64, 64, 0.125f, s_buf, 64, 0);
  k_gemm<32><<<dim3(NN / 32, 1, 3), 256, 0, stream>>>(
      node_feats, 256, 3, 64, 1, W_up_v, 64, 64, 0.125f, v_buf, 192, 64);

  // FUSED edge pipeline: w0/w1/w2 + cmbA + cmbB/cmbC in one kernel
  k_edge<<<EE / 64, 256, 0, stream>>>(efm_h, efm_l, wt_h, wt_l, cmbA, cmbB, cmbC);

  // per-node gather (2 half-waves/node) + tensor product + segment sum
  k_gather<<<NN / 2, 256, 0, stream>>>(snd_p, ya_p, dq_p, mm_attrs,
                                       s_buf, v_buf, cmbA, cmbB, cmbC, offs,
                                       ms_h, ms_l, mv_h, mv_l, dens);

  // node linears on MFMA (RT=32) with density division fused
  k_mgemm<32, 0, false, 1><<<dim3(NN / 32, 1), 256, 0, stream>>>(
      ms_h, ms_l, 320, 320, nullptr, nullptr, 0, 0,
      wt_h + OFF_LINS, wt_l + OFF_LINS, 320, ms2, nullptr, 64, dens);
  k_mgemm<32, 0, false, 3><<<dim3(NN * 3 / 32, 1), 256, 0, stream>>>(
      mv_h, mv_l, 512, 512, nullptr, nullptr, 0, 0,
      wt_h + OFF_LINV, wt_l + OFF_LINV, 512, mv2, nullptr, 64, dens);

  // skip contraction on MFMA (merged s+v, direct write into out (N,64,4))
  k_skipm<<<NN / 32 + NN * 3 / 32, 256, 0, stream>>>(
      ms2, mv2, node_attrs, wt_h, wt_l, out);
}

// Round 13
// 318.791 us; speedup vs baseline: 1.0137x; 1.0137x over previous
//
#include <hip/hip_runtime.h>
#include <hip/hip_bf16.h>

#define NN 8192
#define EE 65536

typedef unsigned short u16;
typedef __attribute__((ext_vector_type(8))) short bf16x8;          // 8 bf16 = 4 VGPRs
typedef __attribute__((ext_vector_type(8))) unsigned short u16x8;  // 16 B load
typedef __attribute__((ext_vector_type(4))) float f32x4;

// Pre-split transposed weight table offsets (elements, shared by h/l planes)
#define OFF_W0    0        // 64 x 32
#define OFF_W1    2048     // 64 x 64
#define OFF_W2    6144     // 64 x 64
#define OFF_W3M   10240    // 512 x 96  (w3*0.125 rows 0..63 | mag*0.25 rows 64..79 | 0)
#define OFF_MAGB  59392    // 512 x 32  (wm slots 3..10, [u*8+j][k])
#define OFF_MAGC  75776    // 128 x 32  (wm slots 11..12, [u*2+j][k]) — contiguous after MAGB
#define OFF_LINS  79872    // 64 x 320
#define OFF_LINV  100352   // 64 x 512
#define OFF_SKS   133120   // 64 x 640  (skip_s reshaped [w][u*10+v], *1/fan)
#define OFF_SKV   174080   // 64 x 640  (skip_v)
#define WT_TOTAL  215040

__device__ __forceinline__ u16 f2bf(float f) {
  __hip_bfloat16 h = __float2bfloat16(f);
  return *reinterpret_cast<u16*>(&h);
}
__device__ __forceinline__ float bf2f(u16 v) {
  union { unsigned int u; float f; } x; x.u = ((unsigned int)v) << 16; return x.f;
}
__device__ __forceinline__ void split2(float x, u16& h, u16& l) {
  __hip_bfloat16 bh = __float2bfloat16(x);
  h = *reinterpret_cast<u16*>(&bh);
  float r = x - __bfloat162float(bh);
  __hip_bfloat16 bl = __float2bfloat16(r);
  l = *reinterpret_cast<u16*>(&bl);
}

#define MFMA(a, b, c) __builtin_amdgcn_mfma_f32_16x16x32_bf16((a), (b), (c), 0, 0, 0)

// ---------------------------------------------------------------------------
// FUSED edge pipeline: efm -> silu(w0) -> silu(w1) -> silu(w2) ->
//   cmbA = [h|efm]@w3m, cmbB/cmbC = efm@magB/C — ONE kernel, no h HBM traffic.
// Block = 64 edges, 256 thr = 4 waves; wave w owns rows w*16..w*16+16.
// R13 change vs R12: outputs are staged per 64-col group into LDS tile Ct
// (C-layout writes, stride 80 => each quad hits a disjoint 8-bank group),
// then stored cooperatively with 128-B-contiguous segments (8 lanes x 16 B
// per row) — R12's scalar u16 C-layout stores ran HBM writes at 32-B
// granularity (~1.4 TB/s measured); this restores full-line writes.
// Numerics identical (same values, routed via LDS).
// ---------------------------------------------------------------------------
__global__ __launch_bounds__(256) void k_edge(
    const u16* __restrict__ efm_h, const u16* __restrict__ efm_l,
    const u16* __restrict__ wt_h, const u16* __restrict__ wt_l,
    u16* __restrict__ cmbA, u16* __restrict__ cmbB, u16* __restrict__ cmbC)
{
  __shared__ u16 Eh[64 * 40], El[64 * 40];   // efm, K=16 zero-padded to 32
  __shared__ u16 Hh[64 * 72], Hl[64 * 72];   // h, K=64
  __shared__ u16 Ct[64 * 80];                // output staging (64 x 64, stride 80)
  const int tid  = threadIdx.x;
  const size_t pos0 = (size_t)blockIdx.x * 64;
  const int wave = tid >> 6, lane = tid & 63;
  const int quad = lane >> 4, lrow = lane & 15;
  const int kbase = quad * 8;
  const int rw = wave * 16;

  // ---- stage efm into LDS (coalesced uint4), zero-pad k=16..31 ----
  #pragma unroll
  for (int i = 0; i < 2; ++i) {
    const int idx = tid + i * 256;           // 512 ops = 64 rows x 8 chunks
    const int r = idx >> 3, c = idx & 7;
    u16* dst = (c & 4) ? El : Eh;
    const u16* src = (c & 4) ? efm_l : efm_h;
    const int cc = c & 3;
    uint4 v = make_uint4(0u, 0u, 0u, 0u);
    if (cc < 2) v = *reinterpret_cast<const uint4*>(&src[(pos0 + r) * 16 + cc * 8]);
    *reinterpret_cast<uint4*>(&dst[r * 40 + cc * 8]) = v;
  }
  __syncthreads();

  // ---- L0: h = silu(efm @ w0), K=32 (padded), N=64 ----
  {
    const bf16x8 fah = *reinterpret_cast<const bf16x8*>(&Eh[(rw + lrow) * 40 + kbase]);
    const bf16x8 fal = *reinterpret_cast<const bf16x8*>(&El[(rw + lrow) * 40 + kbase]);
    #pragma unroll
    for (int nt = 0; nt < 4; ++nt) {
      const size_t bo = (size_t)(nt * 16 + lrow) * 32 + kbase;
      const bf16x8 fbh = *reinterpret_cast<const bf16x8*>(wt_h + OFF_W0 + bo);
      const bf16x8 fbl = *reinterpret_cast<const bf16x8*>(wt_l + OFF_W0 + bo);
      f32x4 acc = {};
      acc = MFMA(fah, fbh, acc); acc = MFMA(fah, fbl, acc); acc = MFMA(fal, fbh, acc);
      #pragma unroll
      for (int r = 0; r < 4; ++r) {
        float t = acc[r];
        t = t / (1.0f + __expf(-t));
        u16 hh, ll; split2(t, hh, ll);
        const int row = rw + quad * 4 + r, col = nt * 16 + lrow;
        Hh[row * 72 + col] = hh; Hl[row * 72 + col] = ll;
      }
    }
  }

  // ---- L1, L2: h = silu(h @ w), K=64, N=64, in-place (A loads precede writes) ----
  #pragma unroll
  for (int layer = 0; layer < 2; ++layer) {
    const int OFF = layer ? OFF_W2 : OFF_W1;
    bf16x8 fah[2], fal[2];
    #pragma unroll
    for (int ks = 0; ks < 2; ++ks) {
      fah[ks] = *reinterpret_cast<const bf16x8*>(&Hh[(rw + lrow) * 72 + ks * 32 + kbase]);
      fal[ks] = *reinterpret_cast<const bf16x8*>(&Hl[(rw + lrow) * 72 + ks * 32 + kbase]);
    }
    f32x4 acc[4] = {};
    #pragma unroll
    for (int nt = 0; nt < 4; ++nt)
      #pragma unroll
      for (int ks = 0; ks < 2; ++ks) {
        const size_t bo = (size_t)(nt * 16 + lrow) * 64 + ks * 32 + kbase;
        const bf16x8 fbh = *reinterpret_cast<const bf16x8*>(wt_h + OFF + bo);
        const bf16x8 fbl = *reinterpret_cast<const bf16x8*>(wt_l + OFF + bo);
        acc[nt] = MFMA(fah[ks], fbh, acc[nt]);
        acc[nt] = MFMA(fah[ks], fbl, acc[nt]);
        acc[nt] = MFMA(fal[ks], fbh, acc[nt]);
      }
    #pragma unroll
    for (int nt = 0; nt < 4; ++nt)
      #pragma unroll
      for (int r = 0; r < 4; ++r) {
        float t = acc[nt][r];
        t = t / (1.0f + __expf(-t));
        u16 hh, ll; split2(t, hh, ll);
        const int row = rw + quad * 4 + r, col = nt * 16 + lrow;
        Hh[row * 72 + col] = hh; Hl[row * 72 + col] = ll;
      }
  }

  // ---- cmbA = [h | efm] @ w3m, K=96, N=512 (8 col-groups, staged stores) ----
  {
    bf16x8 fah[3], fal[3];
    #pragma unroll
    for (int ks = 0; ks < 2; ++ks) {
      fah[ks] = *reinterpret_cast<const bf16x8*>(&Hh[(rw + lrow) * 72 + ks * 32 + kbase]);
      fal[ks] = *reinterpret_cast<const bf16x8*>(&Hl[(rw + lrow) * 72 + ks * 32 + kbase]);
    }
    fah[2] = *reinterpret_cast<const bf16x8*>(&Eh[(rw + lrow) * 40 + kbase]);
    fal[2] = *reinterpret_cast<const bf16x8*>(&El[(rw + lrow) * 40 + kbase]);
    for (int g = 0; g < 8; ++g) {
      #pragma unroll
      for (int nt = 0; nt < 4; ++nt) {
        f32x4 acc = {};
        #pragma unroll
        for (int ks = 0; ks < 3; ++ks) {
          const size_t bo = (size_t)(g * 64 + nt * 16 + lrow) * 96 + ks * 32 + kbase;
          const bf16x8 fbh = *reinterpret_cast<const bf16x8*>(wt_h + OFF_W3M + bo);
          const bf16x8 fbl = *reinterpret_cast<const bf16x8*>(wt_l + OFF_W3M + bo);
          acc = MFMA(fah[ks], fbh, acc); acc = MFMA(fah[ks], fbl, acc); acc = MFMA(fal[ks], fbh, acc);
        }
        #pragma unroll
        for (int r = 0; r < 4; ++r)
          Ct[(rw + quad * 4 + r) * 80 + nt * 16 + lrow] = f2bf(acc[r]);
      }
      __syncthreads();
      #pragma unroll
      for (int i = 0; i < 2; ++i) {
        const int idx = tid + i * 256;       // 512 uint4 = 64 rows x 8 chunks
        const int r2 = idx >> 3, c2 = idx & 7;
        const uint4 v4 = *reinterpret_cast<const uint4*>(&Ct[r2 * 80 + c2 * 8]);
        *reinterpret_cast<uint4*>(&cmbA[(pos0 + r2) * 512 + g * 64 + c2 * 8]) = v4;
      }
      __syncthreads();
    }
  }

  // ---- cmbB/cmbC = efm @ [magB ; magC], K=32, N=640 (10 groups, staged) ----
  {
    const bf16x8 fah = *reinterpret_cast<const bf16x8*>(&Eh[(rw + lrow) * 40 + kbase]);
    const bf16x8 fal = *reinterpret_cast<const bf16x8*>(&El[(rw + lrow) * 40 + kbase]);
    for (int g = 0; g < 10; ++g) {
      #pragma unroll
      for (int nt = 0; nt < 4; ++nt) {
        const int col = g * 64 + nt * 16 + lrow;
        const size_t bo = (size_t)col * 32 + kbase;
        const bf16x8 fbh = *reinterpret_cast<const bf16x8*>(wt_h + OFF_MAGB + bo);
        const bf16x8 fbl = *reinterpret_cast<const bf16x8*>(wt_l + OFF_MAGB + bo);
        f32x4 acc = {};
        acc = MFMA(fah, fbh, acc); acc = MFMA(fah, fbl, acc); acc = MFMA(fal, fbh, acc);
        #pragma unroll
        for (int r = 0; r < 4; ++r)
          Ct[(rw + quad * 4 + r) * 80 + nt * 16 + lrow] = f2bf(acc[r]);
      }
      __syncthreads();
      u16* dst = (g < 8) ? cmbB : cmbC;
      const size_t ors = (g < 8) ? 512 : 128;
      const size_t co  = (g < 8) ? (size_t)g * 64 : (size_t)(g - 8) * 64;
      #pragma unroll
      for (int i = 0; i < 2; ++i) {
        const int idx = tid + i * 256;
        const int r2 = idx >> 3, c2 = idx & 7;
        const uint4 v4 = *reinterpret_cast<const uint4*>(&Ct[r2 * 80 + c2 * 8]);
        *reinterpret_cast<uint4*>(&dst[(pos0 + r2) * ors + co + c2 * 8]) = v4;
      }
      __syncthreads();
    }
  }
}

// ---------------------------------------------------------------------------
// MFMA GEMM, fp32-equivalent via 3-term bf16 split (kept for the node linears).
// RT=32: 4 waves side-by-side over cols (2x1 tiles/wave).
// OUT: 0 = fp32. DDIV: post *= 1/(dens[row/DDIV]+1).
// ---------------------------------------------------------------------------
template<int RT, int OUT, bool SILU, int DDIV>
__global__ __launch_bounds__(256) void k_mgemm(
    const u16* __restrict__ X1h, const u16* __restrict__ X1l, int x1rs, int K1,
    const u16* __restrict__ X2h, const u16* __restrict__ X2l, int x2rs, int K2,
    const u16* __restrict__ Wth, const u16* __restrict__ Wtl, int K,
    void* __restrict__ O1, void* __restrict__ O2, int ors,
    const float* __restrict__ dens)
{
  constexpr int NTN = (RT == 128) ? 4 : 1;
  constexpr int AIT = RT * 8 / 256;
  __shared__ u16 Ah[RT * 40];
  __shared__ u16 Al[RT * 40];
  __shared__ u16 Bh[64 * 40];
  __shared__ u16 Bl[64 * 40];
  const int tid  = threadIdx.x;
  const int row0 = blockIdx.x * RT;
  const int col0 = blockIdx.y * 64;
  const int wave = tid >> 6, lane = tid & 63;
  const int quad = lane >> 4, lrow = lane & 15;
  const int kbase = quad * 8;
  const int rw  = (RT == 128) ? wave * 32 : 0;
  const int ntb = (RT == 128) ? 0 : wave;

  f32x4 acc[2][NTN] = {};

  for (int k0 = 0; k0 < K; k0 += 32) {
    #pragma unroll
    for (int i = 0; i < AIT; ++i) {
      const int idx = tid + i * 256;
      const int b = idx / (RT * 4), rc = idx & (RT * 4 - 1);
      const int r = rc >> 2, c = rc & 3;
      const int gk = k0 + c * 8;
      uint4 v = make_uint4(0u, 0u, 0u, 0u);
      if (gk < K1)
        v = *reinterpret_cast<const uint4*>(&(b ? X1l : X1h)[(size_t)(row0 + r) * x1rs + gk]);
      else if (gk - K1 < K2)
        v = *reinterpret_cast<const uint4*>(&(b ? X2l : X2h)[(size_t)(row0 + r) * x2rs + gk - K1]);
      *reinterpret_cast<uint4*>(&(b ? Al : Ah)[r * 40 + c * 8]) = v;
    }
    #pragma unroll
    for (int i = 0; i < 2; ++i) {
      const int idx = tid + i * 256;
      const int b = idx >> 8, rc = idx & 255;
      const int n = rc >> 2, c = rc & 3;
      const uint4 v = *reinterpret_cast<const uint4*>(
          &(b ? Wtl : Wth)[(size_t)(col0 + n) * K + k0 + c * 8]);
      *reinterpret_cast<uint4*>(&(b ? Bl : Bh)[n * 40 + c * 8]) = v;
    }
    __syncthreads();

    bf16x8 fah[2], fal[2], fbh[NTN], fbl[NTN];
    #pragma unroll
    for (int mt = 0; mt < 2; ++mt) {
      const int ro = (rw + mt * 16 + lrow) * 40 + kbase;
      fah[mt] = *reinterpret_cast<const bf16x8*>(&Ah[ro]);
      fal[mt] = *reinterpret_cast<const bf16x8*>(&Al[ro]);
    }
    #pragma unroll
    for (int nt = 0; nt < NTN; ++nt) {
      const int ro = ((ntb + nt) * 16 + lrow) * 40 + kbase;
      fbh[nt] = *reinterpret_cast<const bf16x8*>(&Bh[ro]);
      fbl[nt] = *reinterpret_cast<const bf16x8*>(&Bl[ro]);
    }
    #pragma unroll
    for (int mt = 0; mt < 2; ++mt)
      #pragma unroll
      for (int nt = 0; nt < NTN; ++nt) {
        acc[mt][nt] = MFMA(fah[mt], fbh[nt], acc[mt][nt]);
        acc[mt][nt] = MFMA(fah[mt], fbl[nt], acc[mt][nt]);
        acc[mt][nt] = MFMA(fal[mt], fbh[nt], acc[mt][nt]);
      }
    __syncthreads();
  }

  #pragma unroll
  for (int mt = 0; mt < 2; ++mt)
    #pragma unroll
    for (int nt = 0; nt < NTN; ++nt)
      #pragma unroll
      for (int r = 0; r < 4; ++r) {
        const int grow = row0 + rw + mt * 16 + quad * 4 + r;
        const int gcol = col0 + (ntb + nt) * 16 + lrow;
        float t = acc[mt][nt][r];
        if (SILU) t = t / (1.0f + __expf(-t));
        if (DDIV > 0) t *= 1.0f / (dens[grow / DDIV] + 1.0f);
        const size_t oi = (size_t)grow * ors + gcol;
        if (OUT == 0) {
          reinterpret_cast<float*>(O1)[oi] = t;
        } else if (OUT == 1) {
          u16 hh, ll;
          split2(t, hh, ll);
          reinterpret_cast<u16*>(O1)[oi] = hh;
          reinterpret_cast<u16*>(O2)[oi] = ll;
        } else {
          reinterpret_cast<u16*>(O1)[oi] = f2bf(t);
        }
      }
}

// ---------------------------------------------------------------------------
// Skip contraction as MFMA GEMM, MERGED, writing DIRECTLY into out (N,64,4).
// ---------------------------------------------------------------------------
__global__ __launch_bounds__(256) void k_skipm(
    const float* __restrict__ ms2, const float* __restrict__ mv2,
    const float* __restrict__ na,
    const u16* __restrict__ wt_h, const u16* __restrict__ wt_l,
    float* __restrict__ out)
{
  __shared__ u16 Ah[32 * 40];
  __shared__ u16 Al[32 * 40];
  __shared__ u16 Bh[64 * 40];
  __shared__ u16 Bl[64 * 40];
  const int tid  = threadIdx.x;
  const bool isv = blockIdx.x >= (NN / 32);
  const int row0 = (isv ? (blockIdx.x - NN / 32) : blockIdx.x) * 32;
  const float* C = isv ? mv2 : ms2;
  const u16* Bth = wt_h + (isv ? OFF_SKV : OFF_SKS);
  const u16* Btl = wt_l + (isv ? OFF_SKV : OFF_SKS);
  const int wave = tid >> 6, lane = tid & 63;
  const int quad = lane >> 4, lrow = lane & 15;
  const int kbase = quad * 8;

  f32x4 acc[2] = {};

  for (int k0 = 0; k0 < 640; k0 += 32) {
    #pragma unroll
    for (int i = 0; i < 4; ++i) {
      const int e = tid + i * 256;
      const int r = e >> 5, kk = e & 31;
      const int k = k0 + kk;
      const int u = k / 10, v = k - u * 10;
      const int row = row0 + r;
      const int n = isv ? (row / 3) : row;
      const float t = C[(size_t)row * 64 + u] * na[n * 10 + v];
      u16 hh, ll;
      split2(t, hh, ll);
      Ah[r * 40 + kk] = hh;
      Al[r * 40 + kk] = ll;
    }
    #pragma unroll
    for (int i = 0; i < 2; ++i) {
      const int idx = tid + i * 256;
      const int b = idx >> 8, rc = idx & 255;
      const int nw = rc >> 2, c = rc & 3;
      const uint4 v4 = *reinterpret_cast<const uint4*>(
          &(b ? Btl : Bth)[(size_t)nw * 640 + k0 + c * 8]);
      *reinterpret_cast<uint4*>(&(b ? Bl : Bh)[nw * 40 + c * 8]) = v4;
    }
    __syncthreads();

    bf16x8 fah[2], fal[2], fbh, fbl;
    #pragma unroll
    for (int mt = 0; mt < 2; ++mt) {
      const int ro = (mt * 16 + lrow) * 40 + kbase;
      fah[mt] = *reinterpret_cast<const bf16x8*>(&Ah[ro]);
      fal[mt] = *reinterpret_cast<const bf16x8*>(&Al[ro]);
    }
    {
      const int ro = (wave * 16 + lrow) * 40 + kbase;
      fbh = *reinterpret_cast<const bf16x8*>(&Bh[ro]);
      fbl = *reinterpret_cast<const bf16x8*>(&Bl[ro]);
    }
    #pragma unroll
    for (int mt = 0; mt < 2; ++mt) {
      acc[mt] = MFMA(fah[mt], fbh, acc[mt]);
      acc[mt] = MFMA(fah[mt], fbl, acc[mt]);
      acc[mt] = MFMA(fal[mt], fbh, acc[mt]);
    }
    __syncthreads();
  }

  #pragma unroll
  for (int mt = 0; mt < 2; ++mt)
    #pragma unroll
    for (int r = 0; r < 4; ++r) {
      const int row = row0 + mt * 16 + quad * 4 + r;
      const int w = wave * 16 + lrow;
      if (isv) {
        const int n = row / 3, i = row - n * 3;
        out[(size_t)n * 256 + w * 4 + 1 + i] = acc[mt][r];
      } else {
        out[(size_t)row * 256 + w * 4] = acc[mt][r];
      }
    }
}

// ---------------------------------------------------------------------------
// fp32 tiled GEMM (node up-projections): OUT = scale * X@W
// ---------------------------------------------------------------------------
template<int RT>
__global__ __launch_bounds__(256) void k_gemm(
    const float* __restrict__ X, int xrs, int xes, int xco, int xcob,
    const float* __restrict__ W, int K, int NOUT,
    float scale, float* __restrict__ OUTp, int ors, int oob)
{
  constexpr int RPT = RT / 16;
  __shared__ float Xs[RT * 65];
  __shared__ float Ws[64 * 64];
  const int tid  = threadIdx.x;
  const int row0 = blockIdx.x * RT;
  const int col0 = blockIdx.y * 64;
  const int z    = blockIdx.z;
  const int xc   = xco + z * xcob;
  const int oo   = z * oob;
  const int ci = tid & 15;
  const int ri = tid >> 4;
  float acc[RPT][4] = {};

  for (int k0 = 0; k0 < K; k0 += 64) {
    const int kc  = (K - k0 >= 64) ? 64 : (K - k0);
    const int ksh = (kc == 64) ? 6 : 4;
    for (int idx = tid; idx < kc * RT; idx += 256) {
      const int r = idx >> ksh, kk = idx & (kc - 1);
      Xs[r * 65 + kk] = X[(size_t)(row0 + r) * xrs + xc + (size_t)(k0 + kk) * xes];
    }
    for (int idx = tid; idx < (kc << 6); idx += 256) {
      const int kk = idx >> 6, c = idx & 63;
      Ws[kk * 64 + c] = W[(size_t)(k0 + kk) * NOUT + col0 + c];
    }
    __syncthreads();
    for (int kk = 0; kk < kc; ++kk) {
      const float4 wv = *reinterpret_cast<const float4*>(&Ws[kk * 64 + ci * 4]);
      #pragma unroll
      for (int j = 0; j < RPT; ++j) {
        const float x = Xs[(ri * RPT + j) * 65 + kk];
        acc[j][0] += x * wv.x; acc[j][1] += x * wv.y;
        acc[j][2] += x * wv.z; acc[j][3] += x * wv.w;
      }
    }
    __syncthreads();
  }

  #pragma unroll
  for (int j = 0; j < RPT; ++j) {
    const int row = row0 + ri * RPT + j;
    *reinterpret_cast<float4*>(OUTp + (size_t)row * ors + oo + col0 + ci * 4) =
        make_float4(acc[j][0] * scale, acc[j][1] * scale, acc[j][2] * scale, acc[j][3] * scale);
  }
}

// ---------------------------------------------------------------------------
// CSR build
// ---------------------------------------------------------------------------
__global__ __launch_bounds__(256) void k_count(const int* __restrict__ rcv, int* __restrict__ counts) {
  const int e = blockIdx.x * 256 + threadIdx.x;
  atomicAdd(&counts[rcv[e]], 1);
}

__global__ __launch_bounds__(1024) void k_scan(const int* __restrict__ counts,
                                               int* __restrict__ offs, int* __restrict__ cursor) {
  __shared__ int part[1024];
  const int tid = threadIdx.x;
  int local[8];
  int s = 0;
  #pragma unroll
  for (int j = 0; j < 8; ++j) { local[j] = s; s += counts[tid * 8 + j]; }
  part[tid] = s;
  __syncthreads();
  for (int off = 1; off < 1024; off <<= 1) {
    int v = 0;
    if (tid >= off) v = part[tid - off];
    __syncthreads();
    part[tid] += v;
    __syncthreads();
  }
  const int base = part[tid] - s;
  #pragma unroll
  for (int j = 0; j < 8; ++j) {
    const int o = base + local[j];
    offs[tid * 8 + j] = o;
    cursor[tid * 8 + j] = o;
  }
  if (tid == 1023) offs[NN] = part[1023];
}

__global__ __launch_bounds__(256) void k_fill(const int* __restrict__ rcv,
                                              int* __restrict__ cursor, int* __restrict__ perm) {
  const int e = blockIdx.x * 256 + threadIdx.x;
  const int pos = atomicAdd(&cursor[rcv[e]], 1);
  perm[pos] = e;
}

// ---------------------------------------------------------------------------
// Build the pre-split, pre-scaled, TRANSPOSED weight table (one pass, ~0.9 MB).
// ---------------------------------------------------------------------------
__global__ __launch_bounds__(256) void k_permw(
    const float* __restrict__ w0, const float* __restrict__ w1,
    const float* __restrict__ w2, const float* __restrict__ w3,
    const float* __restrict__ mag_w, const float* __restrict__ lin_s,
    const float* __restrict__ lin_v, const float* __restrict__ skip_s,
    const float* __restrict__ skip_v,
    u16* __restrict__ wt_h, u16* __restrict__ wt_l)
{
  const int id = blockIdx.x * 256 + threadIdx.x;   // WT_TOTAL threads
  float val = 0.f;
  if (id < OFF_W1) {
    const int i = id - OFF_W0, n = i >> 5, k = i & 31;
    val = (k < 16) ? w0[k * 64 + n] * 0.25f : 0.f;
  } else if (id < OFF_W2) {
    const int i = id - OFF_W1, n = i >> 6, k = i & 63;
    val = w1[k * 64 + n] * 0.125f;
  } else if (id < OFF_W3M) {
    const int i = id - OFF_W2, n = i >> 6, k = i & 63;
    val = w2[k * 64 + n] * 0.125f;
  } else if (id < OFF_MAGB) {
    const int i = id - OFF_W3M, n = i / 96, k = i - n * 96;
    const int u = n >> 3, j = n & 7;
    if (k < 64)      val = (j < 5)  ? w3[k * 320 + j * 64 + u] * 0.125f : 0.f;
    else if (k < 80) val = (j >= 5) ? mag_w[(k - 64) * 832 + (j - 5) * 64 + u] * 0.25f : 0.f;
  } else if (id < OFF_MAGC) {
    const int i = id - OFF_MAGB, n = i >> 5, k = i & 31;
    const int u = n >> 3, j = n & 7;
    val = (k < 16) ? mag_w[k * 832 + (j + 3) * 64 + u] * 0.25f : 0.f;
  } else if (id < OFF_LINS) {
    const int i = id - OFF_MAGC, n = i >> 5, k = i & 31;
    const int u = n >> 1, j = n & 1;
    val = (k < 16) ? mag_w[k * 832 + (j + 11) * 64 + u] * 0.25f : 0.f;
  } else if (id < OFF_LINV) {
    const int i = id - OFF_LINS, n = i / 320, k = i - n * 320;
    val = lin_s[k * 64 + n] * 0.05590169944f;
  } else if (id < OFF_SKS) {
    const int i = id - OFF_LINV, n = i >> 9, k = i & 511;
    val = lin_v[k * 64 + n] * 0.04419417382f;
  } else if (id < OFF_SKV) {
    const int i = id - OFF_SKS, w = i / 640, k = i - w * 640;
    val = skip_s[k * 64 + w] * 0.03952847075f;   // [u*10+v][w], 1/sqrt(640)
  } else if (id < WT_TOTAL) {
    const int i = id - OFF_SKV, w = i / 640, k = i - w * 640;
    val = skip_v[k * 64 + w] * 0.03952847075f;
  } else {
    return;
  }
  u16 hh, ll;
  split2(val, hh, ll);
  wt_h[id] = hh;
  wt_l[id] = ll;
}

// ---------------------------------------------------------------------------
// Permute edge data into receiver-grouped (perm) order + precompute:
//   snd_perm, ya_perm, dq_perm (tanh(q^2)), efm split pair.
// ---------------------------------------------------------------------------
__global__ __launch_bounds__(256) void k_build(
    const int* __restrict__ perm, const int* __restrict__ snd,
    const float* __restrict__ edge_attrs, const float* __restrict__ edge_feats,
    const float* __restrict__ mm_inv, const float* __restrict__ dens_w,
    int* __restrict__ snd_perm, float* __restrict__ ya_perm,
    float* __restrict__ dq_perm, u16* __restrict__ efm_h, u16* __restrict__ efm_l)
{
  const int pos = blockIdx.x * 256 + threadIdx.x;
  const int e = perm[pos];
  const int s = snd[e];
  snd_perm[pos] = s;
  reinterpret_cast<float4*>(ya_perm)[pos] = reinterpret_cast<const float4*>(edge_attrs)[e];
  const float4 ef0 = reinterpret_cast<const float4*>(edge_feats)[e * 2];
  const float4 ef1 = reinterpret_cast<const float4*>(edge_feats)[e * 2 + 1];
  const float4 mi0 = reinterpret_cast<const float4*>(mm_inv)[s * 2];
  const float4 mi1 = reinterpret_cast<const float4*>(mm_inv)[s * 2 + 1];
  float q = ef0.x * dens_w[0] + ef0.y * dens_w[1] + ef0.z * dens_w[2] + ef0.w * dens_w[3]
          + ef1.x * dens_w[4] + ef1.y * dens_w[5] + ef1.z * dens_w[6] + ef1.w * dens_w[7];
  q *= 0.35355339059f;   // 1/sqrt(8)
  dq_perm[pos] = tanhf(q * q);
  float vals[16] = { ef0.x, ef0.y, ef0.z, ef0.w, ef1.x, ef1.y, ef1.z, ef1.w,
                     mi0.x, mi0.y, mi0.z, mi0.w, mi1.x, mi1.y, mi1.z, mi1.w };
  u16 hh[16], ll[16];
  #pragma unroll
  for (int i = 0; i < 16; ++i) split2(vals[i], hh[i], ll[i]);
  reinterpret_cast<uint4*>(&efm_h[(size_t)pos * 16])[0] = reinterpret_cast<uint4*>(hh)[0];
  reinterpret_cast<uint4*>(&efm_h[(size_t)pos * 16])[1] = reinterpret_cast<uint4*>(hh)[1];
  reinterpret_cast<uint4*>(&efm_l[(size_t)pos * 16])[0] = reinterpret_cast<uint4*>(ll)[0];
  reinterpret_cast<uint4*>(&efm_l[(size_t)pos * 16])[1] = reinterpret_cast<uint4*>(ll)[1];
}

// ---------------------------------------------------------------------------
// Gather: TWO half-waves per node (halved serial edge chain, LDS reduction).
// ---------------------------------------------------------------------------
__global__ __launch_bounds__(256) void k_gather(
    const int* __restrict__ snd_perm,
    const float* __restrict__ ya_perm,
    const float* __restrict__ dq_perm,
    const float* __restrict__ mm_attrs,
    const float* __restrict__ s_buf,
    const float* __restrict__ v_buf,
    const u16* __restrict__ cmbA,
    const u16* __restrict__ cmbB,
    const u16* __restrict__ cmbC,
    const int* __restrict__ offs,
    u16* __restrict__ ms_h, u16* __restrict__ ms_l,
    u16* __restrict__ mv_h, u16* __restrict__ mv_l,
    float* __restrict__ dens)
{
  __shared__ float red[2][30][64];
  const int tid  = threadIdx.x;
  const int lane = tid & 63;
  const int nib  = tid >> 7;                 // node within block (0/1)
  const int half = (tid >> 6) & 1;           // segment half (0/1)
  const int n = blockIdx.x * 2 + nib;

  float acc_s[5] = {0.f, 0.f, 0.f, 0.f, 0.f};
  float acc_v[8][3] = {};
  float dacc = 0.f;
  const int start0 = offs[n], end0 = offs[n + 1];
  const int mid = start0 + ((end0 - start0 + 1) >> 1);
  const int start = half ? mid : start0;
  const int end   = half ? end0 : mid;

  int s_nx = 0;
  if (start < end) s_nx = snd_perm[start];
  for (int pos = start; pos < end; ++pos) {
    const int s = s_nx;
    if (pos + 1 < end) s_nx = snd_perm[pos + 1];

    const float4 ya = reinterpret_cast<const float4*>(ya_perm)[pos];
    const float4 mm = reinterpret_cast<const float4*>(mm_attrs)[s];
    dacc += dq_perm[pos];
    const float y0 = ya.x, y1x = ya.y, y1y = ya.z, y1z = ya.w;
    const float m0 = mm.x, m1x = mm.y, m1y = mm.z, m1z = mm.w;
    const float xs  = s_buf[s * 64 + lane];
    const float xvx = v_buf[(s * 3 + 0) * 64 + lane];
    const float xvy = v_buf[(s * 3 + 1) * 64 + lane];
    const float xvz = v_buf[(s * 3 + 2) * 64 + lane];

    const u16x8 ca = *reinterpret_cast<const u16x8*>(&cmbA[((size_t)pos * 64 + lane) * 8]);
    const u16x8 cb = *reinterpret_cast<const u16x8*>(&cmbB[((size_t)pos * 64 + lane) * 8]);
    const unsigned int cc = *reinterpret_cast<const unsigned int*>(&cmbC[((size_t)pos * 64 + lane) * 2]);
    float tpv[5];
    #pragma unroll
    for (int j = 0; j < 5; ++j) tpv[j] = bf2f(ca[j]);
    float wv[13];
    #pragma unroll
    for (int p = 0; p < 3; ++p) wv[p] = bf2f(ca[5 + p]);
    #pragma unroll
    for (int p = 3; p < 11; ++p) wv[p] = bf2f(cb[p - 3]);
    wv[11] = bf2f((u16)(cc & 0xffffu));
    wv[12] = bf2f((u16)(cc >> 16));

    const float ms0  = tpv[0] * xs * y0;
    const float mv0x = tpv[1] * xs * y1x, mv0y = tpv[1] * xs * y1y, mv0z = tpv[1] * xs * y1z;
    const float mv1x = tpv[2] * xvx * y0, mv1y = tpv[2] * xvy * y0, mv1z = tpv[2] * xvz * y0;
    const float ms1  = tpv[3] * (xvx * y1x + xvy * y1y + xvz * y1z) * 0.57735026919f;
    const float crx = xvy * y1z - xvz * y1y;
    const float cry = xvz * y1x - xvx * y1z;
    const float crz = xvx * y1y - xvy * y1x;
    const float mv2x = tpv[4] * crx * 0.70710678119f;
    const float mv2y = tpv[4] * cry * 0.70710678119f;
    const float mv2z = tpv[4] * crz * 0.70710678119f;

    acc_s[0]    += wv[0] * ms0 * m0;
    acc_v[0][0] += wv[1] * ms0 * m1x; acc_v[0][1] += wv[1] * ms0 * m1y; acc_v[0][2] += wv[1] * ms0 * m1z;
    acc_s[1]    += wv[2] * ms1 * m0;
    acc_v[1][0] += wv[3] * ms1 * m1x; acc_v[1][1] += wv[3] * ms1 * m1y; acc_v[1][2] += wv[3] * ms1 * m1z;

#define VV_BLOCK(vx, vy, vz, pw, vslotA, sslot, vslotB)                                   \
    acc_v[vslotA][0] += wv[pw] * (vx) * m0;                                               \
    acc_v[vslotA][1] += wv[pw] * (vy) * m0;                                               \
    acc_v[vslotA][2] += wv[pw] * (vz) * m0;                                               \
    acc_s[sslot] += wv[pw + 1] * ((vx) * m1x + (vy) * m1y + (vz) * m1z) * 0.57735026919f; \
    {                                                                                     \
      const float ccx = (vy) * m1z - (vz) * m1y;                                          \
      const float ccy = (vz) * m1x - (vx) * m1z;                                          \
      const float ccz = (vx) * m1y - (vy) * m1x;                                          \
      acc_v[vslotB][0] += wv[pw + 2] * ccx * 0.70710678119f;                              \
      acc_v[vslotB][1] += wv[pw + 2] * ccy * 0.70710678119f;                              \
      acc_v[vslotB][2] += wv[pw + 2] * ccz * 0.70710678119f;                              \
    }

    VV_BLOCK(mv0x, mv0y, mv0z, 4, 2, 2, 3)
    VV_BLOCK(mv1x, mv1y, mv1z, 7, 4, 3, 5)
    VV_BLOCK(mv2x, mv2y, mv2z, 10, 6, 4, 7)
#undef VV_BLOCK
  }

  // ---- combine the two half-waves of each node via LDS ----
  if (half == 1) {
    #pragma unroll
    for (int j = 0; j < 5; ++j) red[nib][j][lane] = acc_s[j];
    #pragma unroll
    for (int p = 0; p < 8; ++p)
      #pragma unroll
      for (int i = 0; i < 3; ++i) red[nib][5 + p * 3 + i][lane] = acc_v[p][i];
    red[nib][29][lane] = dacc;
  }
  __syncthreads();
  if (half == 0) {
    #pragma unroll
    for (int j = 0; j < 5; ++j) acc_s[j] += red[nib][j][lane];
    #pragma unroll
    for (int p = 0; p < 8; ++p)
      #pragma unroll
      for (int i = 0; i < 3; ++i) acc_v[p][i] += red[nib][5 + p * 3 + i][lane];
    dacc += red[nib][29][lane];

    #pragma unroll
    for (int j = 0; j < 5; ++j) {
      u16 hh, ll;
      split2(acc_s[j], hh, ll);
      ms_h[(size_t)n * 320 + j * 64 + lane] = hh;
      ms_l[(size_t)n * 320 + j * 64 + lane] = ll;
    }
    #pragma unroll
    for (int p = 0; p < 8; ++p)
      #pragma unroll
      for (int i = 0; i < 3; ++i) {
        u16 hh, ll;
        split2(acc_v[p][i], hh, ll);
        mv_h[((size_t)n * 3 + i) * 512 + p * 64 + lane] = hh;
        mv_l[((size_t)n * 3 + i) * 512 + p * 64 + lane] = ll;
      }
    if (lane == 0) dens[n] = dacc;
  }
}

// ---------------------------------------------------------------------------
extern "C" void kernel_launch(void* const* d_in, const int* in_sizes, int n_in,
                              void* d_out, int out_size, void* d_ws, size_t ws_size,
                              hipStream_t stream)
{
  const float* node_attrs = (const float*)d_in[0];
  const float* node_feats = (const float*)d_in[1];
  const float* edge_attrs = (const float*)d_in[2];
  const float* edge_feats = (const float*)d_in[3];
  const int*   edge_index = (const int*)d_in[4];
  const float* mm_inv     = (const float*)d_in[5];
  const float* mm_attrs   = (const float*)d_in[6];
  const float* W_up_s     = (const float*)d_in[7];
  const float* W_up_v     = (const float*)d_in[8];
  const float* w0         = (const float*)d_in[9];
  const float* w1         = (const float*)d_in[10];
  const float* w2         = (const float*)d_in[11];
  const float* w3         = (const float*)d_in[12];
  const float* mag_w      = (const float*)d_in[13];
  const float* dens_w     = (const float*)d_in[14];
  const float* lin_s      = (const float*)d_in[15];
  const float* lin_v      = (const float*)d_in[16];
  const float* skip_s     = (const float*)d_in[17];
  const float* skip_v     = (const float*)d_in[18];
  float* out = (float*)d_out;

  char* wp = (char*)d_ws;
  auto alloc = [&](size_t b) { char* p = wp; wp += (b + 255) & ~(size_t)255; return p; };
  // Total footprint ~250 MB (R12-identical layout).
  float* s_buf  = (float*)alloc((size_t)NN * 64 * 4);       // 2.10 MB
  float* v_buf  = (float*)alloc((size_t)NN * 192 * 4);      // 6.29 MB
  float* ya_p   = (float*)alloc((size_t)EE * 4 * 4);        // 1.05 MB
  float* dq_p   = (float*)alloc((size_t)EE * 4);            // 0.26 MB
  int*   snd_p  = (int*)alloc((size_t)EE * 4);              // 0.26 MB
  u16*   efm_h  = (u16*)alloc((size_t)EE * 16 * 2);         // 2.10 MB
  u16*   efm_l  = (u16*)alloc((size_t)EE * 16 * 2);         // 2.10 MB
  u16*   hA_h   = (u16*)alloc((size_t)EE * 64 * 2);         // 8.39 MB (ms2/mv2 backing)
  u16*   hA_l   = (u16*)alloc((size_t)EE * 64 * 2);         // 8.39 MB
  u16*   hB_h   = (u16*)alloc((size_t)EE * 64 * 2);         // 8.39 MB (ms backing)
  u16*   hB_l   = (u16*)alloc((size_t)EE * 64 * 2);         // 8.39 MB
  u16*   cmbA   = (u16*)alloc((size_t)EE * 512 * 2);        // 67.1 MB
  u16*   cmbB   = (u16*)alloc((size_t)EE * 512 * 2);        // 67.1 MB
  u16*   cmbC   = (u16*)alloc((size_t)EE * 128 * 2);        // 16.8 MB
  u16*   mv_h   = (u16*)alloc((size_t)NN * 1536 * 2);       // 25.2 MB
  u16*   mv_l   = (u16*)alloc((size_t)NN * 1536 * 2);       // 25.2 MB
  float* dens   = (float*)alloc((size_t)NN * 4);
  int*   counts = (int*)alloc((size_t)NN * 4);
  int*   offs   = (int*)alloc((size_t)(NN + 1) * 4);
  int*   cursor = (int*)alloc((size_t)NN * 4);
  int*   perm   = (int*)alloc((size_t)EE * 4);
  u16*   wt_h   = (u16*)alloc((size_t)WT_TOTAL * 2);        // 0.43 MB
  u16*   wt_l   = (u16*)alloc((size_t)WT_TOTAL * 2);        // 0.43 MB
  u16*   ms_h   = hB_h;            // NN*320*2 = 5.25 MB <= 8.39 MB
  u16*   ms_l   = hB_l;
  float* ms2    = (float*)hA_h;    // 2.10 MB <= 8.39 MB
  float* mv2    = (float*)hA_l;    // 6.29 MB <= 8.39 MB

  const int* snd = edge_index;
  const int* rcv = edge_index + EE;

  // CSR + permuted edge data + pre-split transposed weight table
  hipMemsetAsync(counts, 0, (size_t)NN * 4, stream);
  k_count<<<EE / 256, 256, 0, stream>>>(rcv, counts);
  k_scan<<<1, 1024, 0, stream>>>(counts, offs, cursor);
  k_fill<<<EE / 256, 256, 0, stream>>>(rcv, cursor, perm);
  k_build<<<EE / 256, 256, 0, stream>>>(perm, snd, edge_attrs, edge_feats, mm_inv, dens_w,
                                        snd_p, ya_p, dq_p, efm_h, efm_l);
  k_permw<<<(WT_TOTAL + 255) / 256, 256, 0, stream>>>(w0, w1, w2, w3, mag_w, lin_s, lin_v,
                                                     skip_s, skip_v, wt_h, wt_l);

  // node up-projections (fp32 path)
  k_gemm<32><<<dim3(NN / 32, 1, 1), 256, 0, stream>>>(
      node_feats, 256, 1, 0, 0, W_up_s, 64, 64, 0.125f, s_buf, 64, 0);
  k_gemm<32><<<dim3(NN / 32, 1, 3), 256, 0, stream>>>(
      node_feats, 256, 3, 64, 1, W_up_v, 64, 64, 0.125f, v_buf, 192, 64);

  // FUSED edge pipeline: w0/w1/w2 + cmbA + cmbB/cmbC in one kernel
  k_edge<<<EE / 64, 256, 0, stream>>>(efm_h, efm_l, wt_h, wt_l, cmbA, cmbB, cmbC);

  // per-node gather (2 half-waves/node) + tensor product + segment sum
  k_gather<<<NN / 2, 256, 0, stream>>>(snd_p, ya_p, dq_p, mm_attrs,
                                       s_buf, v_buf, cmbA, cmbB, cmbC, offs,
                                       ms_h, ms_l, mv_h, mv_l, dens);

  // node linears on MFMA (RT=32) with density division fused
  k_mgemm<32, 0, false, 1><<<dim3(NN / 32, 1), 256, 0, stream>>>(
      ms_h, ms_l, 320, 320, nullptr, nullptr, 0, 0,
      wt_h + OFF_LINS, wt_l + OFF_LINS, 320, ms2, nullptr, 64, dens);
  k_mgemm<32, 0, false, 3><<<dim3(NN * 3 / 32, 1), 256, 0, stream>>>(
      mv_h, mv_l, 512, 512, nullptr, nullptr, 0, 0,
      wt_h + OFF_LINV, wt_l + OFF_LINV, 512, mv2, nullptr, 64, dens);

  // skip contraction on MFMA (merged s+v, direct write into out (N,64,4))
  k_skipm<<<NN / 32 + NN * 3 / 32, 256, 0, stream>>>(
      ms2, mv2, node_attrs, wt_h, wt_l, out);
}